// Round 10
// baseline (327.865 us; speedup 1.0000x reference)
//
#include <hip/hip_runtime.h>
#include <math.h>

#define BATCH 2
#define SEQ   2048
#define DIM   1024
#define NST   16
#define DTR   64
#define KSL   8                     // split-K slices for x_proj

typedef _Float16 f16x8 __attribute__((ext_vector_type(8)));
typedef float f32x4 __attribute__((ext_vector_type(4)));

__device__ __forceinline__ float softplus_f(float v) {
  return fmaxf(v, 0.f) + log1pf(expf(-fabsf(v)));
}
__device__ __forceinline__ float silu_f(float v) {
  return v / (1.f + expf(-v));
}

__device__ __forceinline__ void gl_lds16(const _Float16* g, _Float16* l) {
  __builtin_amdgcn_global_load_lds(
      (const __attribute__((address_space(1))) void*)g,
      (__attribute__((address_space(3))) void*)l, 16, 0, 0);
}

#define FMA_ROW(i, av)                                        \
  acc[i][0] = fmaf(av, b.x, acc[i][0]);                       \
  acc[i][1] = fmaf(av, b.y, acc[i][1]);                       \
  acc[i][2] = fmaf(av, b.z, acc[i][2]);                       \
  acc[i][3] = fmaf(av, b.w, acc[i][3]);

// ---------------- split fp32 -> hi/lo f16, 3 arrays in one launch ----------
// blocks [0,2048): x (4M elems); [2048,3072): in_proj_w (2M); [3072,3584): out_proj_w (1M)
__global__ __launch_bounds__(256) void k_cvt3(
    const float* __restrict__ in0, _Float16* __restrict__ h0, _Float16* __restrict__ l0,
    const float* __restrict__ in1, _Float16* __restrict__ h1, _Float16* __restrict__ l1,
    const float* __restrict__ in2, _Float16* __restrict__ h2, _Float16* __restrict__ l2) {
  int blk = blockIdx.x;
  const float* in;
  _Float16 *hi, *lo;
  if (blk < 2048)       { in = in0; hi = h0; lo = l0; }
  else if (blk < 3072)  { in = in1; hi = h1; lo = l1; blk -= 2048; }
  else                  { in = in2; hi = h2; lo = l2; blk -= 3072; }
  const int i = (blk * 256 + threadIdx.x) * 8;
  const float4 a = *(const float4*)(in + i);
  const float4 b = *(const float4*)(in + i + 4);
  const float v[8] = {a.x, a.y, a.z, a.w, b.x, b.y, b.z, b.w};
  f16x8 h, l;
#pragma unroll
  for (int j = 0; j < 8; ++j) {
    const _Float16 hh = (_Float16)v[j];
    h[j] = hh;
    l[j] = (_Float16)(v[j] - (float)hh);
  }
  *(f16x8*)(hi + i) = h;
  *(f16x8*)(lo + i) = l;
}

// ---------------- f16x3 NT GEMM: D[m][n] = sum_k A[m,k]*B[n,k], K=LD=1024 ----
template <int EPI>
__global__ __launch_bounds__(256) void kgemm_f16x3(
    const _Float16* __restrict__ Ah, const _Float16* __restrict__ Al,
    const _Float16* __restrict__ Bh, const _Float16* __restrict__ Bl,
    float* __restrict__ out0, float* __restrict__ out1) {
  __shared__ _Float16 sm[16384];  // 32 KB: Ah|Al|Bh|Bl tiles, 128x32 packed
  _Float16* Ash = sm;
  _Float16* Asl = sm + 4096;
  _Float16* Bsh = sm + 8192;
  _Float16* Bsl = sm + 12288;

  const int tid = threadIdx.x;
  const int wid = tid >> 6, lane = tid & 63;
  const int wm = wid >> 1, wn = wid & 1;
  const int m0 = blockIdx.y * 128;
  const int n0 = blockIdx.x * 128;

  const int r0 = wid * 32;
  const int srow = lane >> 2;
  const int skq = (lane & 3) * 8;
  const _Float16* gAh = Ah + (size_t)(m0 + r0 + srow) * 1024 + skq;
  const _Float16* gAl = Al + (size_t)(m0 + r0 + srow) * 1024 + skq;
  const _Float16* gBh = Bh + (size_t)(n0 + r0 + srow) * 1024 + skq;
  const _Float16* gBl = Bl + (size_t)(n0 + r0 + srow) * 1024 + skq;
  _Float16* lAh = Ash + r0 * 32;
  _Float16* lAl = Asl + r0 * 32;
  _Float16* lBh = Bsh + r0 * 32;
  _Float16* lBl = Bsl + r0 * 32;

  const int fr = lane & 15;
  const int fk = (lane >> 4) * 8;

  f32x4 acc[4][4];
#pragma unroll
  for (int i = 0; i < 4; ++i)
#pragma unroll
    for (int j = 0; j < 4; ++j) acc[i][j] = (f32x4)(0.f);

  for (int k0 = 0; k0 < 1024; k0 += 32) {
    __syncthreads();
    gl_lds16(gAh + k0, lAh);
    gl_lds16(gAh + k0 + 16 * 1024, lAh + 512);
    gl_lds16(gAl + k0, lAl);
    gl_lds16(gAl + k0 + 16 * 1024, lAl + 512);
    gl_lds16(gBh + k0, lBh);
    gl_lds16(gBh + k0 + 16 * 1024, lBh + 512);
    gl_lds16(gBl + k0, lBl);
    gl_lds16(gBl + k0 + 16 * 1024, lBl + 512);
    __syncthreads();

    f16x8 ah[4], alo[4], bh[4], blo[4];
#pragma unroll
    for (int i = 0; i < 4; ++i) {
      const int ao = (wm * 64 + i * 16 + fr) * 32 + fk;
      const int bo = (wn * 64 + i * 16 + fr) * 32 + fk;
      ah[i]  = *(const f16x8*)(Ash + ao);
      alo[i] = *(const f16x8*)(Asl + ao);
      bh[i]  = *(const f16x8*)(Bsh + bo);
      blo[i] = *(const f16x8*)(Bsl + bo);
    }
#pragma unroll
    for (int i = 0; i < 4; ++i)
#pragma unroll
      for (int j = 0; j < 4; ++j) {
        acc[i][j] = __builtin_amdgcn_mfma_f32_16x16x32_f16(ah[i], bh[j],
                                                           acc[i][j], 0, 0, 0);
        acc[i][j] = __builtin_amdgcn_mfma_f32_16x16x32_f16(ah[i], blo[j],
                                                           acc[i][j], 0, 0, 0);
        acc[i][j] = __builtin_amdgcn_mfma_f32_16x16x32_f16(alo[i], bh[j],
                                                           acc[i][j], 0, 0, 0);
      }
  }

  const int lr4 = (lane >> 4) * 4, lc = lane & 15;
#pragma unroll
  for (int i = 0; i < 4; ++i) {
#pragma unroll
    for (int j = 0; j < 4; ++j) {
      const int ar = m0 + wm * 64 + i * 16 + lr4;
      const int bc = n0 + wn * 64 + j * 16 + lc;
#pragma unroll
      for (int r = 0; r < 4; ++r) {
        const float v = acc[i][j][r];
        if (EPI == 0) {
          out0[(size_t)(ar + r) * 1024 + bc] = v;
        } else {
          const int bb = bc >> 11, tt = bc & 2047;
          if (ar < 1024) {
            out0[((size_t)bb * 1024 + ar + r) * 2048 + tt] = v;
          } else {
            out1[((size_t)bb * 1024 + (ar + r - 1024)) * 2048 + tt] = v;
          }
        }
      }
    }
  }
}

// ---------------- conv: depthwise k=3, pad=1, along t ----------------
__global__ __launch_bounds__(256) void k_conv(
    const float* __restrict__ xcraw, const float* __restrict__ cw,
    const float* __restrict__ cb, float* __restrict__ xc) {
  const int idx = blockIdx.x * 256 + threadIdx.x;
  const int t0 = (idx & (SEQ / 4 - 1)) * 4;
  const int r = idx >> 9;  // b*DIM + d
  const int d = r & (DIM - 1);
  const float w0 = cw[d * 3 + 0], w1 = cw[d * 3 + 1], w2 = cw[d * 3 + 2];
  const float bias = cb[d];
  const float* in = xcraw + (size_t)r * SEQ;
  float o[4];
#pragma unroll
  for (int j = 0; j < 4; ++j) {
    const int t = t0 + j;
    const float xm = (t > 0) ? in[t - 1] : 0.f;
    const float x0 = in[t];
    const float xp = (t < SEQ - 1) ? in[t + 1] : 0.f;
    o[j] = fmaf(w0, xm, fmaf(w1, x0, fmaf(w2, xp, bias)));
  }
  *(float4*)(xc + (size_t)r * SEQ + t0) = make_float4(o[0], o[1], o[2], o[3]);
}

// ---------------- K2: x_proj split-K GEMM ----------------
__global__ __launch_bounds__(256) void k2_xproj_sk(
    const float* __restrict__ xc, const float* __restrict__ wp,
    float* __restrict__ part) {
  __shared__ float As[16][100];   // [kk][j], +4 pad
  __shared__ float Bs[16][132];   // [kk][t], +4 pad
  const int tid = threadIdx.x;
  const int tile = blockIdx.x;            // 0..31
  const int ks = blockIdx.y;              // 0..KSL-1
  const int b = tile >> 4;
  const int t0 = (tile & 15) * 128;
  const int kbase = ks * (DIM / KSL);     // 128-wide K slice
  const int tx = tid & 15, ty = tid >> 4;
  float acc[6][8] = {{0.f}};
  for (int k = 0; k < DIM / KSL; k += 16) {
    float a_reg[6];
#pragma unroll
    for (int i = 0; i < 6; ++i) {
      const int ii = tid + 256 * i;
      a_reg[i] = wp[(size_t)(ii >> 4) * DIM + kbase + k + (ii & 15)];
    }
    float4 b_reg[2];
#pragma unroll
    for (int r = 0; r < 2; ++r) {
      const int id2 = tid + 256 * r;
      const int krow = id2 >> 5, t4 = (id2 & 31) * 4;
      b_reg[r] = *(const float4*)(xc + ((size_t)b * DIM + kbase + k + krow) *
                                           SEQ + t0 + t4);
    }
    __syncthreads();
#pragma unroll
    for (int i = 0; i < 6; ++i) {
      const int ii = tid + 256 * i;
      As[ii & 15][ii >> 4] = a_reg[i];
    }
#pragma unroll
    for (int r = 0; r < 2; ++r) {
      const int id2 = tid + 256 * r;
      const int krow = id2 >> 5, t4 = (id2 & 31) * 4;
      *(float4*)&Bs[krow][t4] = b_reg[r];
    }
    __syncthreads();
#pragma unroll
    for (int kk = 0; kk < 16; ++kk) {
      const float4 bA = *(const float4*)&Bs[kk][tx * 4];
      const float4 bB = *(const float4*)&Bs[kk][64 + tx * 4];
#pragma unroll
      for (int i = 0; i < 6; ++i) {
        const float a = As[kk][ty + 16 * i];
        acc[i][0] = fmaf(a, bA.x, acc[i][0]);
        acc[i][1] = fmaf(a, bA.y, acc[i][1]);
        acc[i][2] = fmaf(a, bA.z, acc[i][2]);
        acc[i][3] = fmaf(a, bA.w, acc[i][3]);
        acc[i][4] = fmaf(a, bB.x, acc[i][4]);
        acc[i][5] = fmaf(a, bB.y, acc[i][5]);
        acc[i][6] = fmaf(a, bB.z, acc[i][6]);
        acc[i][7] = fmaf(a, bB.w, acc[i][7]);
      }
    }
    __syncthreads();
  }
#pragma unroll
  for (int i = 0; i < 6; ++i) {
    const int j = ty + 16 * i;
    const size_t o = ((size_t)(ks * BATCH + b) * 96 + j) * SEQ + t0;
    *(float4*)(part + o + tx * 4) =
        make_float4(acc[i][0], acc[i][1], acc[i][2], acc[i][3]);
    *(float4*)(part + o + 64 + tx * 4) =
        make_float4(acc[i][4], acc[i][5], acc[i][6], acc[i][7]);
  }
}

// ---------------- reduce split-K partials -> xdbl ----------------
__global__ __launch_bounds__(256) void k_red(const float* __restrict__ part,
                                             float* __restrict__ xdbl) {
  const size_t PL = (size_t)BATCH * 96 * SEQ;  // 393216
  const size_t i4 = ((size_t)blockIdx.x * 256 + threadIdx.x) * 4;
  float4 s = *(const float4*)(part + i4);
#pragma unroll
  for (int ks = 1; ks < KSL; ++ks) {
    const float4 v = *(const float4*)(part + ks * PL + i4);
    s.x += v.x; s.y += v.y; s.z += v.z; s.w += v.w;
  }
  *(float4*)(xdbl + i4) = s;
}

// ---------------- K3: dt_proj GEMM + softplus (fp32, small) ----------------
__global__ __launch_bounds__(256) void k3_dtproj(
    const float* __restrict__ xdbl, const float* __restrict__ dtw,
    const float* __restrict__ dtb, float* __restrict__ delta) {
  __shared__ float As[16][68];
  __shared__ float Bs[16][68];
  const int tid = threadIdx.x;
  const int b = blockIdx.z;
  const int d0 = blockIdx.y * 64;
  const int t0 = blockIdx.x * 64;
  const int tx = tid & 15, ty = tid >> 4;
  const int lrow = tid >> 2, lcol = (tid & 3) * 4;
  const int bk = tid >> 4, bt4 = (tid & 15) * 4;
  float acc[4][4] = {{0.f}};
  for (int k = 0; k < DTR; k += 16) {
    const float4 av =
        *(const float4*)(dtw + (size_t)(d0 + lrow) * DTR + k + lcol);
    const float4 bv =
        *(const float4*)(xdbl + ((size_t)b * 96 + k + bk) * SEQ + t0 + bt4);
    __syncthreads();
    As[lcol + 0][lrow] = av.x; As[lcol + 1][lrow] = av.y;
    As[lcol + 2][lrow] = av.z; As[lcol + 3][lrow] = av.w;
    Bs[bk][bt4 + 0] = bv.x; Bs[bk][bt4 + 1] = bv.y;
    Bs[bk][bt4 + 2] = bv.z; Bs[bk][bt4 + 3] = bv.w;
    __syncthreads();
#pragma unroll
    for (int kk = 0; kk < 16; ++kk) {
      const float4 a = *(const float4*)&As[kk][ty * 4];
      const float4 b = *(const float4*)&Bs[kk][tx * 4];
      FMA_ROW(0, a.x) FMA_ROW(1, a.y) FMA_ROW(2, a.z) FMA_ROW(3, a.w)
    }
  }
#pragma unroll
  for (int i = 0; i < 4; ++i) {
    const int d = d0 + ty * 4 + i;
    const float bias = dtb[d];
    float4 v;
    v.x = softplus_f(acc[i][0] + bias);
    v.y = softplus_f(acc[i][1] + bias);
    v.z = softplus_f(acc[i][2] + bias);
    v.w = softplus_f(acc[i][3] + bias);
    *(float4*)(delta + ((size_t)b * DIM + d) * SEQ + t0 + tx * 4) = v;
  }
}

// ---------------- fused scan: t-parallel Hillis-Steele + n-reduce + gate ----
// Block = one (b,d) row, 1024 threads = 16 waves, wave wv = state n.
// 512-t windows: lane i holds t=8i..8i+7 (8-deep local compose), 6-step
// __shfl_up scan of lane aggregates, reconstruct, y-partials to
// double-buffered LDS; threads<512 reduce 16 n + gate *silu(z) + store.
// 4 windows -> half the shuffles/barriers of the 256-t version (R9).
__global__ __launch_bounds__(1024) void k_scan_fused(
    const float* __restrict__ delta, const float* __restrict__ u,
    const float* __restrict__ xdbl, const float* __restrict__ A_log,
    const float* __restrict__ Dp, const float* __restrict__ z,
    float* __restrict__ y) {
  __shared__ float red[2][NST][516];   // 64.5 KB
  const int tid = threadIdx.x;
  const int wv = tid >> 6;             // 0..15 == n
  const int lane = tid & 63;
  const int idx = blockIdx.x;          // b*DIM + d
  const int b = idx >> 10, d = idx & (DIM - 1);
  const float A = -expf(A_log[d * NST + wv]);
  const float Dprm = Dp[d];
  const float* drow = delta + (size_t)idx * SEQ;
  const float* urow = u + (size_t)idx * SEQ;
  const float* Brow = xdbl + ((size_t)b * 96 + DTR + wv) * SEQ;
  const float* Crow = xdbl + ((size_t)b * 96 + DTR + NST + wv) * SEQ;
  const float* zrow = z + (size_t)idx * SEQ;
  float* yrow = y + (size_t)idx * SEQ;
  float s_c = 0.f;                     // running state carry for (b,d,n)
  const int tl = lane * 8;

  for (int w = 0; w < SEQ / 512; ++w) {
    const int t0 = w * 512;
    const float4 dl0 = *(const float4*)(drow + t0 + tl);
    const float4 dl1 = *(const float4*)(drow + t0 + tl + 4);
    const float4 uu0 = *(const float4*)(urow + t0 + tl);
    const float4 uu1 = *(const float4*)(urow + t0 + tl + 4);
    const float4 Bv0 = *(const float4*)(Brow + t0 + tl);
    const float4 Bv1 = *(const float4*)(Brow + t0 + tl + 4);
    const float4 Cv0 = *(const float4*)(Crow + t0 + tl);
    const float4 Cv1 = *(const float4*)(Crow + t0 + tl + 4);
    const float dls[8] = {dl0.x, dl0.y, dl0.z, dl0.w, dl1.x, dl1.y, dl1.z, dl1.w};
    const float us[8]  = {uu0.x, uu0.y, uu0.z, uu0.w, uu1.x, uu1.y, uu1.z, uu1.w};
    const float Bb[8]  = {Bv0.x, Bv0.y, Bv0.z, Bv0.w, Bv1.x, Bv1.y, Bv1.z, Bv1.w};
    const float Cc[8]  = {Cv0.x, Cv0.y, Cv0.z, Cv0.w, Cv1.x, Cv1.y, Cv1.z, Cv1.w};
    // local (a,b) pairs + inclusive prefixes within the lane's 8 elems
    float p[8], q[8];
    p[0] = __expf(dls[0] * A);
    q[0] = dls[0] * us[0] * Bb[0];
#pragma unroll
    for (int j = 1; j < 8; ++j) {
      const float aj = __expf(dls[j] * A);
      const float bj = dls[j] * us[j] * Bb[j];
      p[j] = aj * p[j - 1];
      q[j] = fmaf(aj, q[j - 1], bj);
    }
    // wave-wide inclusive scan of lane aggregates (compose op)
    float ia = p[7], ib = q[7];
#pragma unroll
    for (int sft = 1; sft < 64; sft <<= 1) {
      const float oa = __shfl_up(ia, sft, 64);
      const float ob = __shfl_up(ib, sft, 64);
      if (lane >= sft) { ib = fmaf(ia, ob, ib); ia = ia * oa; }
    }
    // window aggregate (lane 63) -> carry update
    const float Wa = __shfl(ia, 63, 64);
    const float Wb = __shfl(ib, 63, 64);
    // exclusive prefix for this lane
    float ea = __shfl_up(ia, 1, 64);
    float eb = __shfl_up(ib, 1, 64);
    if (lane == 0) { ea = 1.f; eb = 0.f; }
    const float S = fmaf(ea, s_c, eb);   // state entering lane's segment
    s_c = fmaf(Wa, s_c, Wb);
    // reconstruct per-element states, y-partials
    float yp[8];
#pragma unroll
    for (int j = 0; j < 8; ++j) {
      yp[j] = fmaf(p[j], S, q[j]) * Cc[j];
      if (wv == 0) yp[j] = fmaf(us[j], Dprm, yp[j]);
    }
    *(float4*)&red[w & 1][wv][tl] = make_float4(yp[0], yp[1], yp[2], yp[3]);
    *(float4*)&red[w & 1][wv][tl + 4] = make_float4(yp[4], yp[5], yp[6], yp[7]);
    __syncthreads();
    if (tid < 512) {
      float sum = 0.f;
#pragma unroll
      for (int nn = 0; nn < NST; ++nn) sum += red[w & 1][nn][tid];
      const float zz = zrow[t0 + tid];
      yrow[t0 + tid] = sum * silu_f(zz);
    }
  }
}

// ---------------- transpose + split: y(b,d,t) -> gh/gl (b,t,d) f16 ----------
__global__ __launch_bounds__(256) void k_gt(
    const float* __restrict__ y, _Float16* __restrict__ gh,
    _Float16* __restrict__ gl) {
  __shared__ _Float16 th[64][68];  // [d_local][t_local]
  __shared__ _Float16 tl[64][68];
  const int ti = threadIdx.x;
  const int t0 = blockIdx.x * 64;
  const int d0 = blockIdx.y * 64;
  const int b = blockIdx.z;
  const int c4 = (ti & 15) * 4;
#pragma unroll
  for (int rr = 0; rr < 4; ++rr) {
    const int dl_ = (ti >> 4) + 16 * rr;
    const size_t base = ((size_t)b * DIM + d0 + dl_) * SEQ + t0 + c4;
    const float4 yv = *(const float4*)(y + base);
    const float gy[4] = {yv.x, yv.y, yv.z, yv.w};
#pragma unroll
    for (int k = 0; k < 4; ++k) {
      const _Float16 h = (_Float16)gy[k];
      th[dl_][c4 + k] = h;
      tl[dl_][c4 + k] = (_Float16)(gy[k] - (float)h);
    }
  }
  __syncthreads();
#pragma unroll
  for (int rr = 0; rr < 2; ++rr) {
    const int chunk = ti + 256 * rr;
    const int tloc = chunk >> 3;
    const int dchunk = (chunk & 7) * 8;
    f16x8 hv, lv;
#pragma unroll
    for (int j = 0; j < 8; ++j) {
      hv[j] = th[dchunk + j][tloc];
      lv[j] = tl[dchunk + j][tloc];
    }
    const size_t o = ((size_t)b * SEQ + t0 + tloc) * DIM + d0 + dchunk;
    *(f16x8*)(gh + o) = hv;
    *(f16x8*)(gl + o) = lv;
  }
}

extern "C" void kernel_launch(void* const* d_in, const int* in_sizes, int n_in,
                              void* d_out, int out_size, void* d_ws,
                              size_t ws_size, hipStream_t stream) {
  const float* x          = (const float*)d_in[0];
  const float* in_proj_w  = (const float*)d_in[1];
  const float* conv_w     = (const float*)d_in[2];
  const float* conv_b     = (const float*)d_in[3];
  const float* A_log      = (const float*)d_in[4];
  const float* D_param    = (const float*)d_in[5];
  const float* x_proj_w   = (const float*)d_in[6];
  const float* dt_proj_w  = (const float*)d_in[7];
  const float* dt_proj_b  = (const float*)d_in[8];
  const float* out_proj_w = (const float*)d_in[9];
  float* out = (float*)d_out;
  float* ws = (float*)d_ws;

  const size_t PLANE = (size_t)BATCH * SEQ * DIM;  // 4M floats (16 MB)
  float* xcraw = ws;               // plane0: xcraw -> delta -> gh/gl
  float* delta = ws;
  _Float16* gh = (_Float16*)ws;
  _Float16* gl = (_Float16*)ws + PLANE;
  float* xc    = ws + PLANE;       // (b,d,t) post-conv
  float* zbuf  = ws + 2 * PLANE;   // (b,dz,t) channel-major
  _Float16* xh = (_Float16*)(ws + 3 * PLANE);  // plane3: xh/xl -> part -> ybuf
  _Float16* xl = xh + PLANE;
  float* part  = ws + 3 * PLANE;
  float* ybuf  = ws + 3 * PLANE;
  float* xdbl  = ws + 4 * PLANE;   // (b,96,t) 393216 floats
  _Float16* wih = (_Float16*)(ws + 4 * PLANE + 1572864);
  _Float16* wil = wih + (size_t)2 * DIM * DIM;
  _Float16* woh = wil + (size_t)2 * DIM * DIM;
  _Float16* wol = woh + (size_t)DIM * DIM;

  k_cvt3<<<dim3(3584), 256, 0, stream>>>(x, xh, xl, in_proj_w, wih, wil,
                                         out_proj_w, woh, wol);

  kgemm_f16x3<1><<<dim3(32, 16), 256, 0, stream>>>(wih, wil, xh, xl,
                                                   xcraw, zbuf);
  k_conv<<<dim3((BATCH * DIM * SEQ / 4) / 256), 256, 0, stream>>>(
      xcraw, conv_w, conv_b, xc);
  k2_xproj_sk<<<dim3(32, KSL), 256, 0, stream>>>(xc, x_proj_w, part);
  k_red<<<dim3(384), 256, 0, stream>>>(part, xdbl);
  k3_dtproj<<<dim3(SEQ / 64, DIM / 64, BATCH), 256, 0, stream>>>(
      xdbl, dt_proj_w, dt_proj_b, delta);
  k_scan_fused<<<dim3(BATCH * DIM), 1024, 0, stream>>>(
      delta, xc, xdbl, A_log, D_param, zbuf, ybuf);
  k_gt<<<dim3(SEQ / 64, DIM / 64, BATCH), 256, 0, stream>>>(ybuf, gh, gl);
  kgemm_f16x3<0><<<dim3(8, 32), 256, 0, stream>>>(gh, gl, woh, wol,
                                                  out, nullptr);
}